// Round 1
// baseline (904.409 us; speedup 1.0000x reference)
//
#include <hip/hip_runtime.h>
#include <hip/hip_bf16.h>
#include <cstdint>

#define NTOK 4096
#define NEXP 16
#define HID 2048
#define INTER 1408
#define BK 32
#define LDA 40          // 32 + 8 pad (bf16 elems), keeps 16B alignment (80B rows)
#define MAXTILES 80     // sum ceil(c_e/128) <= 8192/128 + 16 = 80

typedef __attribute__((ext_vector_type(8))) short bf16x8;
typedef __attribute__((ext_vector_type(4))) float f32x4;

// ws int layout: [0..15]=counts [16..31]=counts2 [32..47]=offsets [48]=tile_count
// [64..143]=tile_e [144..223]=tile_mt [256..8447]=topk_id [8448..16639]=topk_w
// [16640..24831]=list_tok [24832..33023]=list_w ; byte 132096: act bf16[8192][1408]

// round-half-up fp32->bf16 pair pack: result = (bf16(hi)<<16)|bf16(lo)
__device__ inline unsigned pack_bf16(float lo, float hi) {
  unsigned a = __builtin_bit_cast(unsigned, lo) + 0x8000u;
  unsigned b = __builtin_bit_cast(unsigned, hi) + 0x8000u;
  return __builtin_amdgcn_perm(b, a, 0x07060302u); // {b[31:16], a[31:16]}
}

__global__ void k_router(const float* __restrict__ logits, int* __restrict__ topk_id,
                         float* __restrict__ topk_w, int* __restrict__ counts) {
  int t = blockIdx.x * blockDim.x + threadIdx.x;
  if (t >= NTOK) return;
  const float* l = logits + (size_t)t * NEXP;
  float b0 = -1e30f, b1 = -1e30f; int i0 = 0, i1 = 0;
#pragma unroll
  for (int i = 0; i < NEXP; i++) {
    float v = l[i];
    if (v > b0) { b1 = b0; i1 = i0; b0 = v; i0 = i; }
    else if (v > b1) { b1 = v; i1 = i; }
  }
  float e = __expf(b1 - b0);
  float inv = 1.f / (1.f + e);
  topk_id[t * 2] = i0; topk_id[t * 2 + 1] = i1;
  topk_w[t * 2] = inv; topk_w[t * 2 + 1] = e * inv;
  atomicAdd(&counts[i0], 1);
  atomicAdd(&counts[i1], 1);
}

__global__ void k_build(int* __restrict__ ws_i) {
  if (threadIdx.x == 0) {
    int off = 0, nt = 0;
    for (int e = 0; e < NEXP; e++) {
      int c = ws_i[e];
      ws_i[32 + e] = off;
      int tiles = (c + 127) >> 7;
      for (int mt = 0; mt < tiles; mt++) { ws_i[64 + nt] = e; ws_i[144 + nt] = mt; nt++; }
      off += c;
    }
    ws_i[48] = nt;
  }
}

__global__ void k_scatter(const int* __restrict__ topk_id, const float* __restrict__ topk_w,
                          int* __restrict__ ws_i, int* __restrict__ list_tok,
                          float* __restrict__ list_w) {
  int t = blockIdx.x * blockDim.x + threadIdx.x;
  if (t >= NTOK) return;
#pragma unroll
  for (int k = 0; k < 2; k++) {
    int e = topk_id[t * 2 + k];
    int slot = ws_i[32 + e] + atomicAdd(&ws_i[16 + e], 1);
    list_tok[slot] = t;
    list_w[slot] = topk_w[t * 2 + k];
  }
}

// gate+up fused GEMM + SwiGLU. Block tile: 128m x 64n, 4 waves (2m x 2n), wave 64x32.
__global__ __launch_bounds__(256, 2) void k_gateup(
    const float* __restrict__ hidden, const float* __restrict__ w_gate,
    const float* __restrict__ w_up, const int* __restrict__ ws_i,
    const int* __restrict__ list_tok, __hip_bfloat16* __restrict__ act) {
  __shared__ unsigned short sA[128 * LDA];
  __shared__ unsigned short sBg[64 * LDA];
  __shared__ unsigned short sBu[64 * LDA];
  __shared__ int sTok[128];

  int tileId = blockIdx.y;
  if (tileId >= ws_i[48]) return;
  int e = ws_i[64 + tileId];
  int mt = ws_i[144 + tileId];
  int c = ws_i[e];
  int offE = ws_i[32 + e];
  int m0 = mt * 128;
  int n0 = blockIdx.x * 64;
  int tid = threadIdx.x;

  if (tid < 128) {
    int r = m0 + tid;
    int rr = r < c ? r : c - 1;
    sTok[tid] = list_tok[offE + rr];
  }
  __syncthreads();

  const float* wg = w_gate + (size_t)e * HID * INTER + n0;
  const float* wu = w_up + (size_t)e * HID * INTER + n0;

  int lane = tid & 63;
  int wave = tid >> 6;
  int wm = wave & 1, wn = wave >> 1;

  f32x4 accG[4][2], accU[4][2];
#pragma unroll
  for (int i = 0; i < 4; i++)
#pragma unroll
    for (int j = 0; j < 2; j++) { accG[i][j] = (f32x4)(0.f); accU[i][j] = (f32x4)(0.f); }

  int ar = tid >> 1;            // A row 0..127
  int ah = (tid & 1) * 16;      // A k sub-offset (elems)
  const float* aSrc = hidden + (size_t)sTok[ar] * HID + ah;

  int bn = tid & 63;            // B col 0..63
  int bkg = tid >> 6;           // k-group 0..3 (8 k each)
  const float* bgSrc = wg + bn + (size_t)(bkg * 8) * INTER;
  const float* buSrc = wu + bn + (size_t)(bkg * 8) * INTER;

  int kq = (lane >> 4) * 8;
  int ml = lane & 15;

  for (int k0 = 0; k0 < HID; k0 += BK) {
    const float4* ap = (const float4*)(aSrc + k0);
    float4 a0 = ap[0], a1 = ap[1], a2 = ap[2], a3 = ap[3];
    float g[8], u[8];
    const float* bg = bgSrc + (size_t)k0 * INTER;
    const float* bu = buSrc + (size_t)k0 * INTER;
#pragma unroll
    for (int j = 0; j < 8; j++) { g[j] = bg[(size_t)j * INTER]; u[j] = bu[(size_t)j * INTER]; }

    __syncthreads();
    {
      uint4 w0 = make_uint4(pack_bf16(a0.x, a0.y), pack_bf16(a0.z, a0.w),
                            pack_bf16(a1.x, a1.y), pack_bf16(a1.z, a1.w));
      uint4 w1 = make_uint4(pack_bf16(a2.x, a2.y), pack_bf16(a2.z, a2.w),
                            pack_bf16(a3.x, a3.y), pack_bf16(a3.z, a3.w));
      *(uint4*)&sA[ar * LDA + ah] = w0;
      *(uint4*)&sA[ar * LDA + ah + 8] = w1;
      *(uint4*)&sBg[bn * LDA + bkg * 8] = make_uint4(
          pack_bf16(g[0], g[1]), pack_bf16(g[2], g[3]),
          pack_bf16(g[4], g[5]), pack_bf16(g[6], g[7]));
      *(uint4*)&sBu[bn * LDA + bkg * 8] = make_uint4(
          pack_bf16(u[0], u[1]), pack_bf16(u[2], u[3]),
          pack_bf16(u[4], u[5]), pack_bf16(u[6], u[7]));
    }
    __syncthreads();

    bf16x8 af[4], bgf[2], buf2[2];
#pragma unroll
    for (int ni = 0; ni < 2; ni++) {
      bgf[ni] = *(const bf16x8*)&sBg[(wn * 32 + ni * 16 + ml) * LDA + kq];
      buf2[ni] = *(const bf16x8*)&sBu[(wn * 32 + ni * 16 + ml) * LDA + kq];
    }
#pragma unroll
    for (int mi = 0; mi < 4; mi++)
      af[mi] = *(const bf16x8*)&sA[(wm * 64 + mi * 16 + ml) * LDA + kq];
#pragma unroll
    for (int mi = 0; mi < 4; mi++)
#pragma unroll
      for (int ni = 0; ni < 2; ni++) {
        accG[mi][ni] = __builtin_amdgcn_mfma_f32_16x16x32_bf16(af[mi], bgf[ni], accG[mi][ni], 0, 0, 0);
        accU[mi][ni] = __builtin_amdgcn_mfma_f32_16x16x32_bf16(af[mi], buf2[ni], accU[mi][ni], 0, 0, 0);
      }
  }

  // epilogue: act = silu(g)*u, bf16 store. C/D: col=lane&15, row=(lane>>4)*4+reg
  int rq = (lane >> 4) * 4;
#pragma unroll
  for (int mi = 0; mi < 4; mi++)
#pragma unroll
    for (int r = 0; r < 4; r++) {
      int mrow = wm * 64 + mi * 16 + rq + r;
      int mglob = m0 + mrow;
      if (mglob < c) {
        size_t arow = (size_t)(offE + mglob);
#pragma unroll
        for (int ni = 0; ni < 2; ni++) {
          float gv = accG[mi][ni][r], uv = accU[mi][ni][r];
          float av = gv / (1.f + __expf(-gv)) * uv;
          int ncol = n0 + wn * 32 + ni * 16 + ml;
          act[arow * INTER + ncol] = __float2bfloat16(av);
        }
      }
    }
}

// down GEMM + weighted atomic scatter. Block tile 128m x 128n, 4 waves (2x2), wave 64x64.
__global__ __launch_bounds__(256, 2) void k_down(
    const __hip_bfloat16* __restrict__ act, const float* __restrict__ w_down,
    const int* __restrict__ ws_i, const int* __restrict__ list_tok,
    const float* __restrict__ list_w, float* __restrict__ out) {
  __shared__ unsigned short sA[128 * LDA];
  __shared__ unsigned short sB[128 * LDA];
  __shared__ int sTok[128];
  __shared__ float sW[128];

  int tileId = blockIdx.y;
  if (tileId >= ws_i[48]) return;
  int e = ws_i[64 + tileId];
  int mt = ws_i[144 + tileId];
  int c = ws_i[e];
  int offE = ws_i[32 + e];
  int m0 = mt * 128;
  int n0 = blockIdx.x * 128;
  int tid = threadIdx.x;

  if (tid < 128) {
    int r = m0 + tid;
    int rr = r < c ? r : c - 1;
    sTok[tid] = list_tok[offE + rr];
    sW[tid] = list_w[offE + rr];
  }
  __syncthreads();

  int lane = tid & 63;
  int wave = tid >> 6;
  int wm = wave & 1, wn = wave >> 1;
  f32x4 acc[4][4];
#pragma unroll
  for (int i = 0; i < 4; i++)
#pragma unroll
    for (int j = 0; j < 4; j++) acc[i][j] = (f32x4)(0.f);

  int ar = tid >> 1;
  int ah = (tid & 1) * 16;  // bf16 elems
  const __hip_bfloat16* aRow;
  {
    int r = m0 + ar;
    int rr = r < c ? r : c - 1;
    aRow = act + (size_t)(offE + rr) * INTER + ah;
  }
  int bn = tid & 127;
  int bkg2 = tid >> 7;  // 0..1, handles k-groups {2*bkg2, 2*bkg2+1}
  const float* bSrc = w_down + (size_t)e * INTER * HID + n0 + bn;

  int kq = (lane >> 4) * 8;
  int ml = lane & 15;

  for (int k0 = 0; k0 < INTER; k0 += BK) {
    const uint4* ap = (const uint4*)(aRow + k0);
    uint4 av0 = ap[0], av1 = ap[1];
    float b[2][8];
#pragma unroll
    for (int tsk = 0; tsk < 2; tsk++) {
      const float* bp = bSrc + (size_t)(k0 + (bkg2 * 2 + tsk) * 8) * HID;
#pragma unroll
      for (int j = 0; j < 8; j++) b[tsk][j] = bp[(size_t)j * HID];
    }

    __syncthreads();
    *(uint4*)&sA[ar * LDA + ah] = av0;
    *(uint4*)&sA[ar * LDA + ah + 8] = av1;
#pragma unroll
    for (int tsk = 0; tsk < 2; tsk++) {
      int kg = bkg2 * 2 + tsk;
      *(uint4*)&sB[bn * LDA + kg * 8] = make_uint4(
          pack_bf16(b[tsk][0], b[tsk][1]), pack_bf16(b[tsk][2], b[tsk][3]),
          pack_bf16(b[tsk][4], b[tsk][5]), pack_bf16(b[tsk][6], b[tsk][7]));
    }
    __syncthreads();

    bf16x8 af[4], bf[4];
#pragma unroll
    for (int mi = 0; mi < 4; mi++)
      af[mi] = *(const bf16x8*)&sA[(wm * 64 + mi * 16 + ml) * LDA + kq];
#pragma unroll
    for (int ni = 0; ni < 4; ni++)
      bf[ni] = *(const bf16x8*)&sB[(wn * 64 + ni * 16 + ml) * LDA + kq];
#pragma unroll
    for (int mi = 0; mi < 4; mi++)
#pragma unroll
      for (int ni = 0; ni < 4; ni++)
        acc[mi][ni] = __builtin_amdgcn_mfma_f32_16x16x32_bf16(af[mi], bf[ni], acc[mi][ni], 0, 0, 0);
  }

  int rq = (lane >> 4) * 4;
#pragma unroll
  for (int mi = 0; mi < 4; mi++)
#pragma unroll
    for (int r = 0; r < 4; r++) {
      int mrow = wm * 64 + mi * 16 + rq + r;
      if (m0 + mrow < c) {
        int t = sTok[mrow];
        float w = sW[mrow];
        float* op = out + (size_t)t * HID + n0 + wn * 64 + ml;
#pragma unroll
        for (int ni = 0; ni < 4; ni++)
          atomicAdd(op + ni * 16, w * acc[mi][ni][r]);
      }
    }
}

extern "C" void kernel_launch(void* const* d_in, const int* in_sizes, int n_in,
                              void* d_out, int out_size, void* d_ws, size_t ws_size,
                              hipStream_t stream) {
  const float* hidden = (const float*)d_in[0];
  const float* logits = (const float*)d_in[1];
  const float* w_gate = (const float*)d_in[2];
  const float* w_up = (const float*)d_in[3];
  const float* w_down = (const float*)d_in[4];
  float* out = (float*)d_out;

  int* ws_i = (int*)d_ws;
  int* topk_id = ws_i + 256;
  float* topk_w = (float*)(ws_i + 8448);
  int* list_tok = ws_i + 16640;
  float* list_w = (float*)(ws_i + 24832);
  __hip_bfloat16* act = (__hip_bfloat16*)((char*)d_ws + 33024 * 4);

  hipMemsetAsync(d_ws, 0, 256 * 4, stream);                       // counts/counts2/tile_count
  hipMemsetAsync(d_out, 0, (size_t)out_size * sizeof(float), stream);

  k_router<<<NTOK / 256, 256, 0, stream>>>(logits, topk_id, topk_w, ws_i);
  k_build<<<1, 64, 0, stream>>>(ws_i);
  k_scatter<<<NTOK / 256, 256, 0, stream>>>(topk_id, topk_w, ws_i, list_tok, list_w);
  k_gateup<<<dim3(INTER / 64, MAXTILES), 256, 0, stream>>>(hidden, w_gate, w_up, ws_i, list_tok, act);
  k_down<<<dim3(HID / 128, MAXTILES), 256, 0, stream>>>(act, w_down, ws_i, list_tok, list_w, out);
}

// Round 2
// 849.438 us; speedup vs baseline: 1.0647x; 1.0647x over previous
//
#include <hip/hip_runtime.h>
#include <hip/hip_bf16.h>
#include <cstdint>

#define NTOK 4096
#define NEXP 16
#define HID 2048
#define INTER 1408
#define BK 32
#define LDA 40          // 32 + 8 pad (bf16 elems), rows are 80 B (16B-aligned)
#define MAXTILES 80     // sum ceil(c_e/128) <= 8192/128 + 16 = 80

typedef __attribute__((ext_vector_type(8))) short bf16x8;
typedef __attribute__((ext_vector_type(4))) float f32x4;

// ws int layout:
//   [0..15]=counts [16..31]=cursors [32..47]=offsets [48]=tile_count
//   [64..143]=tile_e [144..223]=tile_mt
//   [256..]=topk_id(8192) [8448..]=topk_w(8192)
//   [16640..]=list_tok(8192) [24832..]=list_w(8192) [33024..]=slot_of(8192)
// byte 262144: act bf16[8192][1408] (23,068,672 B)
// byte 23330816: AbY bf16[8192][2048] (33,554,432 B)  -- gathered A, later reused as y
// total ~56.9 MB

__device__ inline unsigned pack_bf16(float lo, float hi) {
  unsigned a = __builtin_bit_cast(unsigned, lo) + 0x8000u;
  unsigned b = __builtin_bit_cast(unsigned, hi) + 0x8000u;
  return __builtin_amdgcn_perm(b, a, 0x07060302u); // {b[31:16], a[31:16]}
}

__global__ void k_router(const float* __restrict__ logits, int* __restrict__ topk_id,
                         float* __restrict__ topk_w, int* __restrict__ counts) {
  int t = blockIdx.x * blockDim.x + threadIdx.x;
  if (t >= NTOK) return;
  const float* l = logits + (size_t)t * NEXP;
  float b0 = -1e30f, b1 = -1e30f; int i0 = 0, i1 = 0;
#pragma unroll
  for (int i = 0; i < NEXP; i++) {
    float v = l[i];
    if (v > b0) { b1 = b0; i1 = i0; b0 = v; i0 = i; }
    else if (v > b1) { b1 = v; i1 = i; }
  }
  float e = __expf(b1 - b0);
  float inv = 1.f / (1.f + e);
  topk_id[t * 2] = i0; topk_id[t * 2 + 1] = i1;
  topk_w[t * 2] = inv; topk_w[t * 2 + 1] = e * inv;
  atomicAdd(&counts[i0], 1);
  atomicAdd(&counts[i1], 1);
}

__global__ void k_build(int* __restrict__ ws_i) {
  if (threadIdx.x == 0) {
    int off = 0, nt = 0;
    for (int e = 0; e < NEXP; e++) {
      int c = ws_i[e];
      ws_i[32 + e] = off;
      int tiles = (c + 127) >> 7;
      for (int mt = 0; mt < tiles; mt++) { ws_i[64 + nt] = e; ws_i[144 + nt] = mt; nt++; }
      off += c;
    }
    ws_i[48] = nt;
  }
}

__global__ void k_scatter(const int* __restrict__ topk_id, const float* __restrict__ topk_w,
                          int* __restrict__ ws_i, int* __restrict__ list_tok,
                          float* __restrict__ list_w, int* __restrict__ slot_of) {
  int t = blockIdx.x * blockDim.x + threadIdx.x;
  if (t >= NTOK) return;
#pragma unroll
  for (int k = 0; k < 2; k++) {
    int e = topk_id[t * 2 + k];
    int slot = ws_i[32 + e] + atomicAdd(&ws_i[16 + e], 1);
    list_tok[slot] = t;
    list_w[slot] = topk_w[t * 2 + k];
    slot_of[t * 2 + k] = slot;
  }
}

// gather hidden rows per slot, convert fp32->bf16. One block per slot row.
__global__ __launch_bounds__(256) void k_gather(const float* __restrict__ hidden,
                                                const int* __restrict__ list_tok,
                                                unsigned short* __restrict__ Ab) {
  int s = blockIdx.x, tx = threadIdx.x;
  int t = list_tok[s];
  const float4* src = (const float4*)(hidden + (size_t)t * HID) + tx * 2;
  float4 a = src[0], b = src[1];
  uint4 w = make_uint4(pack_bf16(a.x, a.y), pack_bf16(a.z, a.w),
                       pack_bf16(b.x, b.y), pack_bf16(b.z, b.w));
  ((uint4*)(Ab + (size_t)s * HID))[tx] = w;
}

// gate+up fused GEMM + SwiGLU. Block tile: 128m x 64n (x2 for g,u), 4 waves (2m x 2n).
__global__ __launch_bounds__(256, 4) void k_gateup(
    const unsigned short* __restrict__ Ab, const float* __restrict__ w_gate,
    const float* __restrict__ w_up, const int* __restrict__ ws_i,
    __hip_bfloat16* __restrict__ act) {
  __shared__ unsigned short sA[128 * LDA];
  __shared__ unsigned short sBg[64 * LDA];
  __shared__ unsigned short sBu[64 * LDA];

  int tileId = blockIdx.y;
  if (tileId >= ws_i[48]) return;
  int e = ws_i[64 + tileId];
  int mt = ws_i[144 + tileId];
  int c = ws_i[e];
  int offE = ws_i[32 + e];
  int m0 = mt * 128;
  int n0 = blockIdx.x * 64;
  int tid = threadIdx.x;

  int lane = tid & 63;
  int wave = tid >> 6;
  int wm = wave & 1, wn = wave >> 1;

  // A staging: 2 threads per row, 32 B (16 bf16) each
  int ar = tid >> 1;
  int ah = (tid & 1) * 16;
  int rA = m0 + ar; int rrA = rA < c ? rA : c - 1;
  const unsigned short* aSrc = Ab + (size_t)(offE + rrA) * HID + ah;

  // B staging: 64 cols x 32 k per iter; thread -> (col bn, k-group bkg of 8)
  int bn = tid & 63;
  int bkg = tid >> 6;
  const float* bgSrc = w_gate + (size_t)e * HID * INTER + n0 + bn + (size_t)(bkg * 8) * INTER;
  const float* buSrc = w_up   + (size_t)e * HID * INTER + n0 + bn + (size_t)(bkg * 8) * INTER;

  f32x4 accG[4][2], accU[4][2];
#pragma unroll
  for (int i = 0; i < 4; i++)
#pragma unroll
    for (int j = 0; j < 2; j++) { accG[i][j] = (f32x4)(0.f); accU[i][j] = (f32x4)(0.f); }

  int kq = (lane >> 4) * 8;
  int ml = lane & 15;

  // prologue: prefetch k0 = 0
  uint4 a0r, a1r; float g[8], u[8];
  {
    const uint4* ap = (const uint4*)aSrc;
    a0r = ap[0]; a1r = ap[1];
#pragma unroll
    for (int j = 0; j < 8; j++) { g[j] = bgSrc[(size_t)j * INTER]; u[j] = buSrc[(size_t)j * INTER]; }
  }

  for (int k0 = 0; k0 < HID; k0 += BK) {
    __syncthreads();
    *(uint4*)&sA[ar * LDA + ah] = a0r;
    *(uint4*)&sA[ar * LDA + ah + 8] = a1r;
    *(uint4*)&sBg[bn * LDA + bkg * 8] = make_uint4(
        pack_bf16(g[0], g[1]), pack_bf16(g[2], g[3]),
        pack_bf16(g[4], g[5]), pack_bf16(g[6], g[7]));
    *(uint4*)&sBu[bn * LDA + bkg * 8] = make_uint4(
        pack_bf16(u[0], u[1]), pack_bf16(u[2], u[3]),
        pack_bf16(u[4], u[5]), pack_bf16(u[6], u[7]));
    __syncthreads();

    if (k0 + BK < HID) {
      const uint4* ap = (const uint4*)(aSrc + k0 + BK);
      a0r = ap[0]; a1r = ap[1];
      const float* bg = bgSrc + (size_t)(k0 + BK) * INTER;
      const float* bu = buSrc + (size_t)(k0 + BK) * INTER;
#pragma unroll
      for (int j = 0; j < 8; j++) { g[j] = bg[(size_t)j * INTER]; u[j] = bu[(size_t)j * INTER]; }
    }

    bf16x8 af[4], bgf[2], buf2[2];
#pragma unroll
    for (int ni = 0; ni < 2; ni++) {
      bgf[ni] = *(const bf16x8*)&sBg[(wn * 32 + ni * 16 + ml) * LDA + kq];
      buf2[ni] = *(const bf16x8*)&sBu[(wn * 32 + ni * 16 + ml) * LDA + kq];
    }
#pragma unroll
    for (int mi = 0; mi < 4; mi++)
      af[mi] = *(const bf16x8*)&sA[(wm * 64 + mi * 16 + ml) * LDA + kq];
#pragma unroll
    for (int mi = 0; mi < 4; mi++)
#pragma unroll
      for (int ni = 0; ni < 2; ni++) {
        accG[mi][ni] = __builtin_amdgcn_mfma_f32_16x16x32_bf16(af[mi], bgf[ni], accG[mi][ni], 0, 0, 0);
        accU[mi][ni] = __builtin_amdgcn_mfma_f32_16x16x32_bf16(af[mi], buf2[ni], accU[mi][ni], 0, 0, 0);
      }
  }

  // epilogue: act = silu(g)*u. C/D: col=lane&15, row=(lane>>4)*4+reg
  int rq = (lane >> 4) * 4;
#pragma unroll
  for (int mi = 0; mi < 4; mi++)
#pragma unroll
    for (int r = 0; r < 4; r++) {
      int mrow = wm * 64 + mi * 16 + rq + r;
      int mglob = m0 + mrow;
      if (mglob < c) {
        size_t arow = (size_t)(offE + mglob);
#pragma unroll
        for (int ni = 0; ni < 2; ni++) {
          float gv = accG[mi][ni][r], uv = accU[mi][ni][r];
          float av = gv / (1.f + __expf(-gv)) * uv;
          int ncol = n0 + wn * 32 + ni * 16 + ml;
          act[arow * INTER + ncol] = __float2bfloat16(av);
        }
      }
    }
}

// down GEMM, weighted, atomic-free: writes y[slot][HID] bf16. Block tile 128m x 64n.
__global__ __launch_bounds__(256, 4) void k_down(
    const __hip_bfloat16* __restrict__ act, const float* __restrict__ w_down,
    const int* __restrict__ ws_i, const float* __restrict__ list_w,
    unsigned short* __restrict__ y) {
  __shared__ unsigned short sA[128 * LDA];
  __shared__ unsigned short sB[64 * LDA];
  __shared__ float sW[128];

  int tileId = blockIdx.y;
  if (tileId >= ws_i[48]) return;
  int e = ws_i[64 + tileId];
  int mt = ws_i[144 + tileId];
  int c = ws_i[e];
  int offE = ws_i[32 + e];
  int m0 = mt * 128;
  int n0 = blockIdx.x * 64;
  int tid = threadIdx.x;

  if (tid < 128) {
    int r = m0 + tid;
    int rr = r < c ? r : c - 1;
    sW[tid] = list_w[offE + rr];
  }

  int lane = tid & 63;
  int wave = tid >> 6;
  int wm = wave & 1, wn = wave >> 1;
  f32x4 acc[4][2];
#pragma unroll
  for (int i = 0; i < 4; i++)
#pragma unroll
    for (int j = 0; j < 2; j++) acc[i][j] = (f32x4)(0.f);

  int ar = tid >> 1;
  int ah = (tid & 1) * 16;
  int rA = m0 + ar; int rrA = rA < c ? rA : c - 1;
  const unsigned short* aSrc = (const unsigned short*)act + (size_t)(offE + rrA) * INTER + ah;

  int bn = tid & 63;
  int bkg = tid >> 6;
  const float* bSrc = w_down + (size_t)e * INTER * HID + (size_t)(bkg * 8) * HID + n0 + bn;

  int kq = (lane >> 4) * 8;
  int ml = lane & 15;

  uint4 a0r, a1r; float b[8];
  {
    const uint4* ap = (const uint4*)aSrc;
    a0r = ap[0]; a1r = ap[1];
#pragma unroll
    for (int j = 0; j < 8; j++) b[j] = bSrc[(size_t)j * HID];
  }

  for (int k0 = 0; k0 < INTER; k0 += BK) {
    __syncthreads();
    *(uint4*)&sA[ar * LDA + ah] = a0r;
    *(uint4*)&sA[ar * LDA + ah + 8] = a1r;
    *(uint4*)&sB[bn * LDA + bkg * 8] = make_uint4(
        pack_bf16(b[0], b[1]), pack_bf16(b[2], b[3]),
        pack_bf16(b[4], b[5]), pack_bf16(b[6], b[7]));
    __syncthreads();

    if (k0 + BK < INTER) {
      const uint4* ap = (const uint4*)(aSrc + k0 + BK);
      a0r = ap[0]; a1r = ap[1];
      const float* bp = bSrc + (size_t)(k0 + BK) * HID;
#pragma unroll
      for (int j = 0; j < 8; j++) b[j] = bp[(size_t)j * HID];
    }

    bf16x8 af[4], bf[2];
#pragma unroll
    for (int ni = 0; ni < 2; ni++)
      bf[ni] = *(const bf16x8*)&sB[(wn * 32 + ni * 16 + ml) * LDA + kq];
#pragma unroll
    for (int mi = 0; mi < 4; mi++)
      af[mi] = *(const bf16x8*)&sA[(wm * 64 + mi * 16 + ml) * LDA + kq];
#pragma unroll
    for (int mi = 0; mi < 4; mi++)
#pragma unroll
      for (int ni = 0; ni < 2; ni++)
        acc[mi][ni] = __builtin_amdgcn_mfma_f32_16x16x32_bf16(af[mi], bf[ni], acc[mi][ni], 0, 0, 0);
  }

  int rq = (lane >> 4) * 4;
#pragma unroll
  for (int mi = 0; mi < 4; mi++)
#pragma unroll
    for (int r = 0; r < 4; r++) {
      int mrow = wm * 64 + mi * 16 + rq + r;
      if (m0 + mrow < c) {
        float w = sW[mrow];
        size_t yrow = (size_t)(offE + m0 + mrow);
#pragma unroll
        for (int ni = 0; ni < 2; ni++) {
          int ncol = n0 + wn * 32 + ni * 16 + ml;
          float v = w * acc[mi][ni][r];
          y[yrow * HID + ncol] = (unsigned short)(pack_bf16(v, 0.f) & 0xffffu);
        }
      }
    }
}

// out[t] = y[slot0] + y[slot1], full coalesced row writes (covers every element).
__global__ __launch_bounds__(256) void k_combine(const unsigned short* __restrict__ y,
                                                 const int* __restrict__ slot_of,
                                                 float* __restrict__ out) {
  int t = blockIdx.x, tx = threadIdx.x;
  size_t s0 = (size_t)slot_of[t * 2], s1 = (size_t)slot_of[t * 2 + 1];
  uint4 v0 = ((const uint4*)(y + s0 * HID))[tx];
  uint4 v1 = ((const uint4*)(y + s1 * HID))[tx];
  float r[8];
  unsigned p0[4] = {v0.x, v0.y, v0.z, v0.w};
  unsigned p1[4] = {v1.x, v1.y, v1.z, v1.w};
#pragma unroll
  for (int i = 0; i < 4; i++) {
    float lo0 = __builtin_bit_cast(float, p0[i] << 16);
    float hi0 = __builtin_bit_cast(float, p0[i] & 0xffff0000u);
    float lo1 = __builtin_bit_cast(float, p1[i] << 16);
    float hi1 = __builtin_bit_cast(float, p1[i] & 0xffff0000u);
    r[i * 2] = lo0 + lo1; r[i * 2 + 1] = hi0 + hi1;
  }
  float4* op = (float4*)(out + (size_t)t * HID) + tx * 2;
  op[0] = make_float4(r[0], r[1], r[2], r[3]);
  op[1] = make_float4(r[4], r[5], r[6], r[7]);
}

extern "C" void kernel_launch(void* const* d_in, const int* in_sizes, int n_in,
                              void* d_out, int out_size, void* d_ws, size_t ws_size,
                              hipStream_t stream) {
  const float* hidden = (const float*)d_in[0];
  const float* logits = (const float*)d_in[1];
  const float* w_gate = (const float*)d_in[2];
  const float* w_up = (const float*)d_in[3];
  const float* w_down = (const float*)d_in[4];
  float* out = (float*)d_out;

  int* ws_i = (int*)d_ws;
  int* topk_id = ws_i + 256;
  float* topk_w = (float*)(ws_i + 8448);
  int* list_tok = ws_i + 16640;
  float* list_w = (float*)(ws_i + 24832);
  int* slot_of = ws_i + 33024;
  __hip_bfloat16* act = (__hip_bfloat16*)((char*)d_ws + 262144);
  unsigned short* AbY = (unsigned short*)((char*)d_ws + 23330816);  // gathered A, then y

  hipMemsetAsync(d_ws, 0, 256 * 4, stream);  // counts/cursors/tile_count

  k_router<<<NTOK / 256, 256, 0, stream>>>(logits, topk_id, topk_w, ws_i);
  k_build<<<1, 64, 0, stream>>>(ws_i);
  k_scatter<<<NTOK / 256, 256, 0, stream>>>(topk_id, topk_w, ws_i, list_tok, list_w, slot_of);
  k_gather<<<NTOK * 2, 256, 0, stream>>>(hidden, list_tok, AbY);
  k_gateup<<<dim3(INTER / 64, MAXTILES), 256, 0, stream>>>(AbY, w_gate, w_up, ws_i, act);
  k_down<<<dim3(HID / 64, MAXTILES), 256, 0, stream>>>(act, w_down, ws_i, list_w, AbY);
  k_combine<<<NTOK, 256, 0, stream>>>(AbY, slot_of, out);
}